// Round 6
// baseline (1705.146 us; speedup 1.0000x reference)
//
#include <hip/hip_runtime.h>

#define SEQ 512
#define BATCH 64
#define NN 1024
#define SS 64
#define NT 512            // threads per block; each thread owns neurons i and i+512

// barrier that does NOT drain vmcnt: each wave settles its own LDS/SMEM ops,
// then s_barrier. Outstanding global loads/stores stay in flight across it.
#define RAW_BARRIER() asm volatile("s_waitcnt lgkmcnt(0)\n\ts_barrier" ::: "memory")

// ---- transpose W1,W2 (1024x1024 f32) into workspace: Wt[i*N+j] = W[j*N+i] ----
__global__ void transpose2(const float* __restrict__ A, const float* __restrict__ Bm,
                           float* __restrict__ At, float* __restrict__ Bt) {
    __shared__ float tile[32][33];
    const float* in = blockIdx.z ? Bm : A;
    float* out      = blockIdx.z ? Bt : At;
    int bx = blockIdx.x * 32, by = blockIdx.y * 32;
    int tx = threadIdx.x, ty = threadIdx.y;   // block 32x8
#pragma unroll
    for (int r = 0; r < 32; r += 8)
        tile[ty + r][tx] = in[(by + ty + r) * NN + (bx + tx)];
    __syncthreads();
#pragma unroll
    for (int r = 0; r < 32; r += 8)
        out[(bx + ty + r) * NN + (by + tx)] = tile[tx][ty + r];
}

// 16-lane inclusive prefix scan via DPP row_shr (pure VALU, no LDS).
__device__ __forceinline__ int dpp_scan16(int x) {
    x += __builtin_amdgcn_update_dpp(0, x, 0x111, 0xF, 0xF, false); // row_shr:1
    x += __builtin_amdgcn_update_dpp(0, x, 0x112, 0xF, 0xF, false); // row_shr:2
    x += __builtin_amdgcn_update_dpp(0, x, 0x114, 0xF, 0xF, false); // row_shr:4
    x += __builtin_amdgcn_update_dpp(0, x, 0x118, 0xF, 0xF, false); // row_shr:8
    return x;
}

// ---- main LIF kernel: 1 block per batch element, 512 threads, 2 neurons/thread.
// __launch_bounds__(512, 2): 8 waves/block = 2 waves/EU -> VGPR cap 256, so the
// full up-to-128-register gather prefetch stays resident (R4 spill lesson).
__global__ __launch_bounds__(NT, 2) void lif_kernel(
    const float* __restrict__ W1T, const float* __restrict__ W2T,
    const float* __restrict__ decay1, const float* __restrict__ decay2,
    const float* __restrict__ th1, const float* __restrict__ th2,
    const float* __restrict__ init1, const float* __restrict__ init2,
    const int* __restrict__ inp_ids, const int* __restrict__ inp_num,
    float* __restrict__ out)
{
    const int b    = blockIdx.x;
    const int i    = threadIdx.x;      // n0 = i, n1 = i + 512
    const int lane = i & 63;
    const int wid  = i >> 6;           // 0..7; neuron group g0 = wid, g1 = 8 + wid
    const int n0   = i;
    const int n1   = i + NT;

    __shared__ int slotsA[NN];       // only used on (rare) layer-1 spike steps
    __shared__ int wt[2][2][16];     // [step parity][layer][group], packed cnt|cnt2<<16

    float v1_0 = init1[b * NN + n0], v1_1 = init1[b * NN + n1];
    float v2_0 = init2[b * NN + n0], v2_1 = init2[b * NN + n1];
    const float d1_0 = decay1[n0], d1_1 = decay1[n1];
    const float d2_0 = decay2[n0], d2_1 = decay2[n1];
    const float t1_0 = th1[n0],   t1_1 = th1[n1];
    const float t2_0 = th2[n0],   t2_1 = th2[n1];
    const float t1b_0 = __fmul_rn(0.9f, t1_0), t1b_1 = __fmul_rn(0.9f, t1_1);
    const float t2b_0 = __fmul_rn(0.9f, t2_0), t2b_1 = __fmul_rn(0.9f, t2_1);
    const float omd1_0 = __fadd_rn(1.0f, -d1_0), omd1_1 = __fadd_rn(1.0f, -d1_1);
    const float omd2_0 = __fadd_rn(1.0f, -d2_0), omd2_1 = __fadd_rn(1.0f, -d2_1);

    // output layout (floats): ids1 | ids2 | cnt1 | cnt2 | st1 | st2
    float* out_ids1 = out;
    float* out_ids2 = out + (size_t)SEQ * BATCH * SS;
    float* out_cnt1 = out + (size_t)2 * SEQ * BATCH * SS;
    float* out_cnt2 = out_cnt1 + (size_t)SEQ * BATCH * 2;
    float* out_st1  = out_cnt2 + (size_t)SEQ * BATCH * 2;
    float* out_st2  = out_st1  + (size_t)SEQ * BATCH * NN;

    const unsigned long long lmask_lt = (1ull << lane) - 1ull;

    // identity-init slotsA: stale remainder reads in the rare gather stay in [0,1023]
    slotsA[n0] = n0;
    slotsA[n1] = n1;

    // ---- prologue: prefetch full num-limited gather(0), both columns ----
    float a0[64], a1[64];
    int num = inp_num[b];
    const int* idsg = inp_ids + (size_t)b * SS;   // block-uniform -> s_load path
    {
        const int nch = (num + 15) >> 4;
#pragma unroll
        for (int c = 0; c < 4; ++c)
            if (c < nch) {                         // block-uniform branch
#pragma unroll
                for (int j = 0; j < 16; ++j) {
                    const size_t base = ((size_t)idsg[c * 16 + j] << 10);
                    a0[c * 16 + j] = W1T[base + n0];
                    a1[c * 16 + j] = W1T[base + n1];   // same addr + 2KB imm offset
                }
            }
    }

    for (int t = 0; t < SEQ; ++t) {
        const int p  = t & 1;
        const int tn = (t + 1 < SEQ) ? t + 1 : 0;  // wrapped: last-iter prefetch harmless
        const int num_next = inp_num[tn * BATCH + b];
        const int* idsn = inp_ids + ((size_t)tn * BATCH + b) * SS;

        // ---- layer 1 accumulate from resident a0/a1 (loads issued last iter) ----
        float I1_0, I1_1;
        {
            float x0 = 0.0f, x1 = 0.0f, x2 = 0.0f, x3 = 0.0f;
            float y0 = 0.0f, y1 = 0.0f, y2 = 0.0f, y3 = 0.0f;
#pragma unroll
            for (int c = 0; c < 4; ++c) {
                const int lim = num - (c << 4);
                if (lim >= 16) {
#pragma unroll
                    for (int j = 0; j < 16; j += 4) {
                        x0 = __fadd_rn(x0, a0[c * 16 + j + 0]);
                        x1 = __fadd_rn(x1, a0[c * 16 + j + 1]);
                        x2 = __fadd_rn(x2, a0[c * 16 + j + 2]);
                        x3 = __fadd_rn(x3, a0[c * 16 + j + 3]);
                        y0 = __fadd_rn(y0, a1[c * 16 + j + 0]);
                        y1 = __fadd_rn(y1, a1[c * 16 + j + 1]);
                        y2 = __fadd_rn(y2, a1[c * 16 + j + 2]);
                        y3 = __fadd_rn(y3, a1[c * 16 + j + 3]);
                    }
                } else if (lim > 0) {
#pragma unroll
                    for (int j = 0; j < 16; j += 4) {
                        x0 = __fadd_rn(x0, (j + 0 < lim) ? a0[c * 16 + j + 0] : 0.0f);
                        x1 = __fadd_rn(x1, (j + 1 < lim) ? a0[c * 16 + j + 1] : 0.0f);
                        x2 = __fadd_rn(x2, (j + 2 < lim) ? a0[c * 16 + j + 2] : 0.0f);
                        x3 = __fadd_rn(x3, (j + 3 < lim) ? a0[c * 16 + j + 3] : 0.0f);
                        y0 = __fadd_rn(y0, (j + 0 < lim) ? a1[c * 16 + j + 0] : 0.0f);
                        y1 = __fadd_rn(y1, (j + 1 < lim) ? a1[c * 16 + j + 1] : 0.0f);
                        y2 = __fadd_rn(y2, (j + 2 < lim) ? a1[c * 16 + j + 2] : 0.0f);
                        y3 = __fadd_rn(y3, (j + 3 < lim) ? a1[c * 16 + j + 3] : 0.0f);
                    }
                }
            }
            I1_0 = __fadd_rn(__fadd_rn(x0, x1), __fadd_rn(x2, x3));
            I1_1 = __fadd_rn(__fadd_rn(y0, y1), __fadd_rn(y2, y3));
        }

        v1_0 = __fadd_rn(__fmul_rn(d1_0, v1_0), __fmul_rn(omd1_0, I1_0));
        v1_1 = __fadd_rn(__fmul_rn(d1_1, v1_1), __fmul_rn(omd1_1, I1_1));
        const bool spk1_0  = v1_0 > t1_0,  spk1_1  = v1_1 > t1_1;
        const bool near1_0 = v1_0 > t1b_0, near1_1 = v1_1 > t1b_1;
        const unsigned long long balL = __ballot(spk1_0);   // neurons wid*64+lane
        const unsigned long long balLn = __ballot(near1_0);
        const unsigned long long balH = __ballot(spk1_1);   // neurons (8+wid)*64+lane
        const unsigned long long balHn = __ballot(near1_1);
        if (lane == 0) {
            wt[p][0][wid]     = (int)__popcll(balL) | ((int)__popcll(balLn) << 16);
            wt[p][0][8 + wid] = (int)__popcll(balH) | ((int)__popcll(balHn) << 16);
        }

        // ---- speculative layer 2 (I2 = 0, the overwhelmingly common case) ----
        const float v2s_0 = __fmul_rn(d2_0, v2_0);
        const float v2s_1 = __fmul_rn(d2_1, v2_1);
        {
            const unsigned long long c1 = __ballot(v2s_0 > t2_0);
            const unsigned long long c2 = __ballot(v2s_0 > t2b_0);
            const unsigned long long c3 = __ballot(v2s_1 > t2_1);
            const unsigned long long c4 = __ballot(v2s_1 > t2b_1);
            if (lane == 0) {
                wt[p][1][wid]     = (int)__popcll(c1) | ((int)__popcll(c2) << 16);
                wt[p][1][8 + wid] = (int)__popcll(c3) | ((int)__popcll(c4) << 16);
            }
        }

        // ---- prefetch gather(t+1), both columns, num-limited; issued PRE-barrier
        // so the loads are older than this step's NT stores and their latency is
        // covered by barrier + scans + stores + loop-back ----
        {
            const int nch = (num_next + 15) >> 4;
#pragma unroll
            for (int c = 0; c < 4; ++c)
                if (c < nch) {
#pragma unroll
                    for (int j = 0; j < 16; ++j) {
                        const size_t base = ((size_t)idsn[c * 16 + j] << 10);
                        a0[c * 16 + j] = W1T[base + n0];
                        a1[c * 16 + j] = W1T[base + n1];
                    }
                }
        }

        RAW_BARRIER();                              // single barrier (common case)

        // ---- scan layer 1 (16 groups; this wave owns groups wid and 8+wid) ----
        int xA = dpp_scan16(wt[p][0][lane & 15]);
        const int totPackA = __builtin_amdgcn_readlane(xA, 15);
        const int offA_lo  = wid ? __builtin_amdgcn_readlane(xA, wid - 1) : 0;
        const int offA_hi  = __builtin_amdgcn_readlane(xA, wid + 7);
        const int totalA  = totPackA & 0xFFFF;
        const int total2A = totPackA >> 16;
        const int spk_lt1_0 = (offA_lo & 0xFFFF) + (int)__popcll(balL & lmask_lt);
        const int spk_lt1_1 = (offA_hi & 0xFFFF) + (int)__popcll(balH & lmask_lt);
        const int slot1_0 = spk1_0 ? spk_lt1_0 : (totalA + n0 - spk_lt1_0);
        const int slot1_1 = spk1_1 ? spk_lt1_1 : (totalA + n1 - spk_lt1_1);
        if (spk1_0) v1_0 = 0.0f;
        if (spk1_1) v1_1 = 0.0f;

        // ---- layer 2 resolve: accept speculation, or rare corrective path ----
        bool spk2_0, spk2_1;
        if (totalA > 0) {
            if (spk1_0) slotsA[spk_lt1_0] = n0;
            if (spk1_1) slotsA[spk_lt1_1] = n1;
            RAW_BARRIER();                          // rare
            float I2_0 = 0.0f, I2_1 = 0.0f;
            const int kfull = totalA >> 4;
            const int krem  = totalA & 15;
            int kbase = 0;
            for (int r = 0; r < kfull; ++r, kbase += 16) {
                float u[16], w[16];
#pragma unroll
                for (int j = 0; j < 16; ++j) {
                    const size_t base = ((size_t)slotsA[kbase + j] << 10);
                    u[j] = W2T[base + n0];
                    w[j] = W2T[base + n1];
                }
#pragma unroll
                for (int j = 0; j < 16; ++j) {
                    I2_0 = __fadd_rn(I2_0, u[j]);
                    I2_1 = __fadd_rn(I2_1, w[j]);
                }
            }
            if (krem) {
                float u[16], w[16];
#pragma unroll
                for (int j = 0; j < 16; ++j) {      // stale entries valid (identity init)
                    const size_t base = ((size_t)slotsA[kbase + j] << 10);
                    u[j] = W2T[base + n0];
                    w[j] = W2T[base + n1];
                }
#pragma unroll
                for (int j = 0; j < 16; ++j)
                    if (j < krem) {
                        I2_0 = __fadd_rn(I2_0, u[j]);
                        I2_1 = __fadd_rn(I2_1, w[j]);
                    }
            }
            const float v2r_0 = __fadd_rn(__fmul_rn(d2_0, v2_0), __fmul_rn(omd2_0, I2_0));
            const float v2r_1 = __fadd_rn(__fmul_rn(d2_1, v2_1), __fmul_rn(omd2_1, I2_1));
            spk2_0 = v2r_0 > t2_0;
            spk2_1 = v2r_1 > t2_1;
            const unsigned long long c1 = __ballot(spk2_0);
            const unsigned long long c2 = __ballot(v2r_0 > t2b_0);
            const unsigned long long c3 = __ballot(spk2_1);
            const unsigned long long c4 = __ballot(v2r_1 > t2b_1);
            if (lane == 0) {
                wt[p][1][wid]     = (int)__popcll(c1) | ((int)__popcll(c2) << 16);
                wt[p][1][8 + wid] = (int)__popcll(c3) | ((int)__popcll(c4) << 16);
            }
            RAW_BARRIER();                          // rare
            v2_0 = v2r_0;
            v2_1 = v2r_1;
        } else {
            v2_0 = v2s_0;
            v2_1 = v2s_1;
            spk2_0 = v2_0 > t2_0;
            spk2_1 = v2_1 > t2_1;
        }

        // ---- scan layer 2 (wt[p][1] is spec or corrected) ----
        const unsigned long long balL2 = __ballot(spk2_0);
        const unsigned long long balH2 = __ballot(spk2_1);
        int xB = dpp_scan16(wt[p][1][lane & 15]);
        const int totPackB = __builtin_amdgcn_readlane(xB, 15);
        const int offB_lo  = wid ? __builtin_amdgcn_readlane(xB, wid - 1) : 0;
        const int offB_hi  = __builtin_amdgcn_readlane(xB, wid + 7);
        const int totalB   = totPackB & 0xFFFF;
        const int total2B  = totPackB >> 16;
        const int spk_lt2_0 = (offB_lo & 0xFFFF) + (int)__popcll(balL2 & lmask_lt);
        const int spk_lt2_1 = (offB_hi & 0xFFFF) + (int)__popcll(balH2 & lmask_lt);
        const int slot2_0 = spk2_0 ? spk_lt2_0 : (totalB + n0 - spk_lt2_0);
        const int slot2_1 = spk2_1 ? spk_lt2_1 : (totalB + n1 - spk_lt2_1);
        if (spk2_0) v2_0 = 0.0f;
        if (spk2_1) v2_1 = 0.0f;

        // ---- stores for step t (NT, fire-and-forget; never drained at barriers) ----
        const size_t row = (size_t)t * BATCH + b;
        if (slot1_0 < SS)
            __builtin_nontemporal_store((float)n0, &out_ids1[row * SS + slot1_0]);
        if (slot1_1 < SS)
            __builtin_nontemporal_store((float)n1, &out_ids1[row * SS + slot1_1]);
        if (slot2_0 < SS)
            __builtin_nontemporal_store((float)n0, &out_ids2[row * SS + slot2_0]);
        if (slot2_1 < SS)
            __builtin_nontemporal_store((float)n1, &out_ids2[row * SS + slot2_1]);
        if (i == 0) {
            __builtin_nontemporal_store((float)totalA,  &out_cnt1[row * 2 + 0]);
            __builtin_nontemporal_store((float)total2A, &out_cnt1[row * 2 + 1]);
            __builtin_nontemporal_store((float)totalB,  &out_cnt2[row * 2 + 0]);
            __builtin_nontemporal_store((float)total2B, &out_cnt2[row * 2 + 1]);
        }
        __builtin_nontemporal_store(v1_0, &out_st1[row * NN + n0]);
        __builtin_nontemporal_store(v1_1, &out_st1[row * NN + n1]);
        __builtin_nontemporal_store(v2_0, &out_st2[row * NN + n0]);
        __builtin_nontemporal_store(v2_1, &out_st2[row * NN + n1]);

        num  = num_next;
        idsg = idsn;
    }
}

extern "C" void kernel_launch(void* const* d_in, const int* in_sizes, int n_in,
                              void* d_out, int out_size, void* d_ws, size_t ws_size,
                              hipStream_t stream) {
    const float* W1     = (const float*)d_in[0];
    const float* W2     = (const float*)d_in[1];
    const float* decay1 = (const float*)d_in[2];
    const float* decay2 = (const float*)d_in[3];
    const float* th1    = (const float*)d_in[4];
    const float* th2    = (const float*)d_in[5];
    const float* init1  = (const float*)d_in[6];
    const float* init2  = (const float*)d_in[7];
    const int* inp_ids  = (const int*)d_in[8];
    const int* inp_num  = (const int*)d_in[9];
    float* out = (float*)d_out;

    float* W1T = (float*)d_ws;
    float* W2T = W1T + (size_t)NN * NN;

    dim3 tb(32, 8, 1), tg(NN / 32, NN / 32, 2);
    transpose2<<<tg, tb, 0, stream>>>(W1, W2, W1T, W2T);
    lif_kernel<<<BATCH, NT, 0, stream>>>(W1T, W2T, decay1, decay2, th1, th2,
                                         init1, init2, inp_ids, inp_num, out);
}

// Round 7
// 1612.188 us; speedup vs baseline: 1.0577x; 1.0577x over previous
//
#include <hip/hip_runtime.h>

#define SEQ 512
#define BATCH 64
#define NN 1024
#define SS 64

// barrier that does NOT drain vmcnt: each wave settles its own LDS/SMEM ops,
// then s_barrier. Outstanding global loads/stores stay in flight across it.
#define RAW_BARRIER() asm volatile("s_waitcnt lgkmcnt(0)\n\ts_barrier" ::: "memory")

// ---- transpose W1,W2 (1024x1024 f32) into workspace: Wt[i*N+j] = W[j*N+i] ----
__global__ void transpose2(const float* __restrict__ A, const float* __restrict__ Bm,
                           float* __restrict__ At, float* __restrict__ Bt) {
    __shared__ float tile[32][33];
    const float* in = blockIdx.z ? Bm : A;
    float* out      = blockIdx.z ? Bt : At;
    int bx = blockIdx.x * 32, by = blockIdx.y * 32;
    int tx = threadIdx.x, ty = threadIdx.y;   // block 32x8
#pragma unroll
    for (int r = 0; r < 32; r += 8)
        tile[ty + r][tx] = in[(by + ty + r) * NN + (bx + tx)];
    __syncthreads();
#pragma unroll
    for (int r = 0; r < 32; r += 8)
        out[(bx + ty + r) * NN + (by + tx)] = tile[tx][ty + r];
}

// 16-lane inclusive prefix scan via DPP row_shr (pure VALU, no LDS).
__device__ __forceinline__ int dpp_scan16(int x) {
    x += __builtin_amdgcn_update_dpp(0, x, 0x111, 0xF, 0xF, false); // row_shr:1
    x += __builtin_amdgcn_update_dpp(0, x, 0x112, 0xF, 0xF, false); // row_shr:2
    x += __builtin_amdgcn_update_dpp(0, x, 0x114, 0xF, 0xF, false); // row_shr:4
    x += __builtin_amdgcn_update_dpp(0, x, 0x118, 0xF, 0xF, false); // row_shr:8
    return x;
}

// ---- main LIF kernel: 1 block per batch element, thread n = neuron n ----
// __launch_bounds__(1024, 4): 16 waves/block = 4 waves/EU -> VGPR cap 128.
// (R4 lesson: lower cap spills the a[64] prefetch to scratch -> 5 GB HBM traffic.)
__global__ __launch_bounds__(1024, 4) void lif_kernel(
    const float* __restrict__ W1T, const float* __restrict__ W2T,
    const float* __restrict__ decay1, const float* __restrict__ decay2,
    const float* __restrict__ th1, const float* __restrict__ th2,
    const float* __restrict__ init1, const float* __restrict__ init2,
    const int* __restrict__ inp_ids, const int* __restrict__ inp_num,
    float* __restrict__ out)
{
    const int b = blockIdx.x;
    const int n = threadIdx.x;
    const int lane = n & 63;
    const int wid  = n >> 6;

    __shared__ int slotsA[NN];       // only used on (rare) layer-1 spike steps
    __shared__ int wt[2][2][16];     // [step parity][layer][wave], packed cnt|cnt2<<16

    float v1 = init1[b * NN + n];
    float v2 = init2[b * NN + n];
    const float d1 = decay1[n], d2 = decay2[n];
    const float t1 = th1[n],    t2 = th2[n];
    const float t1b = __fmul_rn(0.9f, t1);
    const float t2b = __fmul_rn(0.9f, t2);
    const float omd1 = __fadd_rn(1.0f, -d1);
    const float omd2 = __fadd_rn(1.0f, -d2);

    // output layout (floats): ids1 | ids2 | cnt1 | cnt2 | st1 | st2
    float* out_ids1 = out;
    float* out_ids2 = out + (size_t)SEQ * BATCH * SS;
    float* out_cnt1 = out + (size_t)2 * SEQ * BATCH * SS;
    float* out_cnt2 = out_cnt1 + (size_t)SEQ * BATCH * 2;
    float* out_st1  = out_cnt2 + (size_t)SEQ * BATCH * 2;
    float* out_st2  = out_st1  + (size_t)SEQ * BATCH * NN;

    const unsigned long long lmask_lt = (1ull << lane) - 1ull;

    // identity-init slotsA: stale remainder reads in the rare gather stay in [0,1023]
    slotsA[n] = n;

    // ---- prologue ----
    // num pipeline: num_cur = num(0), num_nx = num(1), num(t+2) in flight each step.
    int num_cur = inp_num[b];
    int num_nx  = inp_num[BATCH + b];
    // ids pipeline: idv_a[lane] = ids(1)[lane] (every wave loads the same 256B,
    // coalesced; consumed via readlane with compile-time lane indices).
    // Issued BEFORE the gather so consuming it never waits on gather loads.
    int idv_a = inp_ids[((size_t)BATCH + b) * SS + lane];
    // gather(0): direct scalar-ids path (one-time serial s_load chain is fine)
    float a[64];
    {
        const int* idsg0 = inp_ids + (size_t)b * SS;
        const int nch = (num_cur + 15) >> 4;
#pragma unroll
        for (int c = 0; c < 4; ++c)
            if (c < nch) {                        // block-uniform branch
#pragma unroll
                for (int j = 0; j < 16; ++j)
                    a[c * 16 + j] = W1T[((size_t)idsg0[c * 16 + j] << 10) + n];
            }
    }

    for (int t = 0; t < SEQ; ++t) {
        const int p   = t & 1;
        const int tn2 = (t + 2 < SEQ) ? t + 2 : 0;   // wrap: tail loads harmless

        // ---- early issues (older than this step's gather in vmcnt order) ----
        const int idv_b  = inp_ids[((size_t)tn2 * BATCH + b) * SS + lane]; // ids(t+2)
        const int num_n2 = inp_num[tn2 * BATCH + b];                       // num(t+2)

        const int nch_cur = (num_cur + 15) >> 4;
        const int nch_nx  = (num_nx  + 15) >> 4;

        // ---- interleaved: accumulate gather(t) chunk c, then re-issue chunk c
        // for gather(t+1). Loads get the whole step (~barrier+scan+stores+next
        // accumulate lead-in) to stream back from L1/L2. WAR on a[] is safe:
        // in-order issue means the fadds read a[c] before the load overwrites it.
        float I1;
        {
            float s0 = 0.0f, s1 = 0.0f, s2 = 0.0f, s3 = 0.0f;
#pragma unroll
            for (int c = 0; c < 4; ++c) {
                const int lim = num_cur - (c << 4);
                if (lim >= 16) {
#pragma unroll
                    for (int j = 0; j < 16; j += 4) {
                        s0 = __fadd_rn(s0, a[c * 16 + j + 0]);
                        s1 = __fadd_rn(s1, a[c * 16 + j + 1]);
                        s2 = __fadd_rn(s2, a[c * 16 + j + 2]);
                        s3 = __fadd_rn(s3, a[c * 16 + j + 3]);
                    }
                } else if (lim > 0) {
#pragma unroll
                    for (int j = 0; j < 16; j += 4) {
                        s0 = __fadd_rn(s0, (j + 0 < lim) ? a[c * 16 + j + 0] : 0.0f);
                        s1 = __fadd_rn(s1, (j + 1 < lim) ? a[c * 16 + j + 1] : 0.0f);
                        s2 = __fadd_rn(s2, (j + 2 < lim) ? a[c * 16 + j + 2] : 0.0f);
                        s3 = __fadd_rn(s3, (j + 3 < lim) ? a[c * 16 + j + 3] : 0.0f);
                    }
                }
                if (c < nch_nx) {                  // issue chunk c of gather(t+1)
#pragma unroll
                    for (int j = 0; j < 16; ++j) {
                        const int sid = __builtin_amdgcn_readlane(idv_a, c * 16 + j);
                        a[c * 16 + j] = W1T[((size_t)sid << 10) + n];
                    }
                }
            }
            I1 = __fadd_rn(__fadd_rn(s0, s1), __fadd_rn(s2, s3));
        }

        v1 = __fadd_rn(__fmul_rn(d1, v1), __fmul_rn(omd1, I1));
        const bool spk1  = v1 > t1;
        const bool near1 = v1 > t1b;
        const unsigned long long bal1 = __ballot(spk1);
        const unsigned long long bal2 = __ballot(near1);
        if (lane == 0)
            wt[p][0][wid] = (int)__popcll(bal1) | ((int)__popcll(bal2) << 16);

        // ---- speculative layer 2 (I2 = 0, the overwhelmingly common case) ----
        const float v2s = __fmul_rn(d2, v2);
        {
            const unsigned long long c1 = __ballot(v2s > t2);
            const unsigned long long c2 = __ballot(v2s > t2b);
            if (lane == 0)
                wt[p][1][wid] = (int)__popcll(c1) | ((int)__popcll(c2) << 16);
        }

        RAW_BARRIER();                              // single barrier (common case)

        // ---- scan layer 1 ----
        int xA = dpp_scan16(wt[p][0][lane & 15]);
        const int totPackA = __builtin_amdgcn_readlane(xA, 15);
        const int offPackA = wid ? __builtin_amdgcn_readlane(xA, wid - 1) : 0;
        const int totalA  = totPackA & 0xFFFF;
        const int total2A = totPackA >> 16;
        const int waveoff = offPackA & 0xFFFF;
        const int spk_lt1 = waveoff + (int)__popcll(bal1 & lmask_lt);
        const int slot1   = spk1 ? spk_lt1 : (totalA + n - spk_lt1);
        if (spk1) v1 = 0.0f;

        // ---- layer 2 resolve: accept speculation, or rare corrective path ----
        bool spk2;
        if (totalA > 0) {
            if (spk1) slotsA[spk_lt1] = n;          // only spiking slots needed
            RAW_BARRIER();                          // rare
            float I2 = 0.0f;
            const int kfull = totalA >> 4;
            const int krem  = totalA & 15;
            int kbase = 0;
            for (int r = 0; r < kfull; ++r, kbase += 16) {
                float aa[16];
#pragma unroll
                for (int j = 0; j < 16; ++j)
                    aa[j] = W2T[(slotsA[kbase + j] << 10) + n];
#pragma unroll
                for (int j = 0; j < 16; ++j)
                    I2 = __fadd_rn(I2, aa[j]);
            }
            if (krem) {
                float aa[16];
#pragma unroll
                for (int j = 0; j < 16; ++j)        // stale entries valid (identity init)
                    aa[j] = W2T[(slotsA[kbase + j] << 10) + n];
#pragma unroll
                for (int j = 0; j < 16; ++j)
                    if (j < krem) I2 = __fadd_rn(I2, aa[j]);
            }
            const float v2r = __fadd_rn(__fmul_rn(d2, v2), __fmul_rn(omd2, I2));
            spk2 = v2r > t2;
            const unsigned long long c1 = __ballot(spk2);
            const unsigned long long c2 = __ballot(v2r > t2b);
            if (lane == 0)
                wt[p][1][wid] = (int)__popcll(c1) | ((int)__popcll(c2) << 16);
            RAW_BARRIER();                          // rare
            v2 = v2r;
        } else {
            v2 = v2s;
            spk2 = v2 > t2;
        }

        // ---- scan layer 2 (wt[p][1] is spec or corrected) ----
        int xB = dpp_scan16(wt[p][1][lane & 15]);
        const int totPackB = __builtin_amdgcn_readlane(xB, 15);
        const int offPackB = wid ? __builtin_amdgcn_readlane(xB, wid - 1) : 0;
        const int totalB   = totPackB & 0xFFFF;
        const int total2B  = totPackB >> 16;
        const int waveoffB = offPackB & 0xFFFF;
        const unsigned long long bal3 = __ballot(spk2);
        const int spk_lt2 = waveoffB + (int)__popcll(bal3 & lmask_lt);
        const int slot2   = spk2 ? spk_lt2 : (totalB + n - spk_lt2);
        if (spk2) v2 = 0.0f;

        // ---- stores for step t (NT, fire-and-forget; never drained at barriers) ----
        const size_t row = (size_t)t * BATCH + b;
        if (slot1 < SS)
            __builtin_nontemporal_store((float)n, &out_ids1[row * SS + slot1]);
        if (slot2 < SS)
            __builtin_nontemporal_store((float)n, &out_ids2[row * SS + slot2]);
        if (n == 0) {
            __builtin_nontemporal_store((float)totalA,  &out_cnt1[row * 2 + 0]);
            __builtin_nontemporal_store((float)total2A, &out_cnt1[row * 2 + 1]);
            __builtin_nontemporal_store((float)totalB,  &out_cnt2[row * 2 + 0]);
            __builtin_nontemporal_store((float)total2B, &out_cnt2[row * 2 + 1]);
        }
        __builtin_nontemporal_store(v1, &out_st1[row * NN + n]);
        __builtin_nontemporal_store(v2, &out_st2[row * NN + n]);

        // ---- rotate pipelines ----
        num_cur = num_nx;
        num_nx  = num_n2;
        idv_a   = idv_b;
    }
}

extern "C" void kernel_launch(void* const* d_in, const int* in_sizes, int n_in,
                              void* d_out, int out_size, void* d_ws, size_t ws_size,
                              hipStream_t stream) {
    const float* W1     = (const float*)d_in[0];
    const float* W2     = (const float*)d_in[1];
    const float* decay1 = (const float*)d_in[2];
    const float* decay2 = (const float*)d_in[3];
    const float* th1    = (const float*)d_in[4];
    const float* th2    = (const float*)d_in[5];
    const float* init1  = (const float*)d_in[6];
    const float* init2  = (const float*)d_in[7];
    const int* inp_ids  = (const int*)d_in[8];
    const int* inp_num  = (const int*)d_in[9];
    float* out = (float*)d_out;

    float* W1T = (float*)d_ws;
    float* W2T = W1T + (size_t)NN * NN;

    dim3 tb(32, 8, 1), tg(NN / 32, NN / 32, 2);
    transpose2<<<tg, tb, 0, stream>>>(W1, W2, W1T, W2T);
    lif_kernel<<<BATCH, NN, 0, stream>>>(W1T, W2T, decay1, decay2, th1, th2,
                                         init1, init2, inp_ids, inp_num, out);
}